// Round 12
// baseline (74.067 us; speedup 1.0000x reference)
//
#include <hip/hip_runtime.h>
#include <math.h>

// DGP loss — ROUND 12: R11 (best, 73.9us) + LOSSLESS bf16-packed LDS tile.
// After bf16_rne the low 16 mantissa bits are zero -> pack 2 channels/dword
// (exact); unpack = shift/and (exact). LDS 43.5KB -> 23.2KB => 6 blocks/CU
// (was 3; R8 OccupancyPercent=22, VALUBusy=16 -> latency-bound, more resident
// waves is the lever). Identical f32 values flow through the identical op
// chain -> bit-exact with R5-R11 (absmax 0.0 all rounds).
// Keeps: XCD-contiguous oy-run swizzle (R11, -2.8us), max-MLP staging (R9,
// -8us), per-block plain partial stores + fin kernel (R10 taught us
// single-address atomics serialize), fma screen with cold exact numpy chain.

#define HP    188
#define IMW   192
#define NCH   32
#define TW    64
#define HWC   68          // 64 + 4 halo cols
#define NR    5           // 1 output row + 4 halo rows
#define PLANE (IMW * IMW)
#define NBLK  (3 * HP * 2)   // 1128 = 141 * 8
#define NSLOT (8 * NR * HWC) // 2720 quad-slots (4 channels each)
#define SPT   11             // ceil(2720/256) slots per thread

__device__ __forceinline__ unsigned bf16_bits(float f) {
    unsigned u = __float_as_uint(f);
    return (u + 0x7fffu + ((u >> 16) & 1u)) >> 16;   // RNE to bf16, return bits
}
__device__ __forceinline__ float bf16_rne(float f) {
    unsigned u = __float_as_uint(f);
    u += 0x7fffu + ((u >> 16) & 1u);
    u &= 0xffff0000u;
    return __uint_as_float(u);
}
// unpack: low half -> first channel, high half -> second (exact)
__device__ __forceinline__ float lo_f(unsigned p) { return __uint_as_float(p << 16); }
__device__ __forceinline__ float hi_f(unsigned p) { return __uint_as_float(p & 0xffff0000u); }

__global__ __launch_bounds__(256) void dgp_tiled(
    const float* __restrict__ S,   // [2,32,192,192] bf16-grid values in f32
    const float* __restrict__ D,   // [2,1,192,192]
    double* __restrict__ partials) // [NBLK] plain stores
{
    __shared__ __align__(8) uint2 smp[8][NR][HWC];   // 21760 B packed bf16 x4
    __shared__ float  rd[NR][HWC];                   // 1360 B
    __shared__ double wsum[4];

    const int tid = threadIdx.x;
    const int tx  = tid & 63;
    const int tg  = tid >> 6;

    // ---- XCD-aware tile decode: XCD (l&7) owns a contiguous oy-run ----
    const int l   = blockIdx.x;
    const int xcd = l & 7;
    const int g   = xcd * 141 + (l >> 3);
    const int c   = g / HP;              // column 0..5 = (b, xtile)
    const int oy  = g - c * HP;
    const int b   = c / 3;
    const int ox0 = (c - 3 * b) * TW;

    // ---------- phase 1: issue ALL staging loads (max MLP) ----------
    float dv[2];
#pragma unroll
    for (int s = 0; s < 2; ++s) {
        const int t = tid + 256 * s;
        float d = 1.0f;
        if (t < NR * HWC) {
            const int i   = t / HWC;
            const int col = t - i * HWC;
            const int gc  = ox0 + col;
            if (gc < IMW) d = D[(b * IMW + (oy + i)) * IMW + gc];
        }
        dv[s] = d;
    }
    float4 sv[SPT];
#pragma unroll
    for (int s = 0; s < SPT; ++s) {
        const int t = tid + 256 * s;
        float4 v = make_float4(0.f, 0.f, 0.f, 0.f);
        if (t < NSLOT) {
            const int q   = t / (NR * HWC);
            const int rem = t - q * (NR * HWC);
            const int i   = rem / HWC;
            const int col = rem - i * HWC;
            const int gc  = ox0 + col;
            if (gc < IMW) {
                const int base = ((b * NCH + 4 * q) * IMW + (oy + i)) * IMW + gc;
                v.x = S[base];
                v.y = S[base + PLANE];
                v.z = S[base + 2 * PLANE];
                v.w = S[base + 3 * PLANE];
            }
        }
        sv[s] = v;
    }

    // ---------- phase 2: rne + pack + LDS write ----------
#pragma unroll
    for (int s = 0; s < 2; ++s) {
        const int t = tid + 256 * s;
        if (t < NR * HWC) {
            const int i   = t / HWC;
            const int col = t - i * HWC;
            rd[i][col] = 1.0f / (bf16_rne(dv[s]) + 1e-6f);
        }
    }
#pragma unroll
    for (int s = 0; s < SPT; ++s) {
        const int t = tid + 256 * s;
        if (t < NSLOT) {
            const int q   = t / (NR * HWC);
            const int rem = t - q * (NR * HWC);
            const int i   = rem / HWC;
            const int col = rem - i * HWC;
            const float4 v = sv[s];
            uint2 pk;
            pk.x = bf16_bits(v.x) | (__float_as_uint(bf16_rne(v.y)) & 0xffff0000u);
            pk.y = bf16_bits(v.z) | (__float_as_uint(bf16_rne(v.w)) & 0xffff0000u);
            smp[q][i][col] = pk;
        }
    }
    __syncthreads();

    // ---------- compute: 64 positions x 4 tap-groups (6 taps each) ----------
    double acc = 0.0;
    const int ox = ox0 + tx;
    if (ox < HP) {
        float cs[NCH];
#pragma unroll
        for (int q = 0; q < 8; ++q) {
            const uint2 p = smp[q][2][tx + 2];
            cs[4 * q + 0] = lo_f(p.x);
            cs[4 * q + 1] = hi_f(p.x);
            cs[4 * q + 2] = lo_f(p.y);
            cs[4 * q + 3] = hi_f(p.y);
        }
        const float rc = rd[2][tx + 2];

        for (int k = 0; k < 6; ++k) {
            int t = tg * 6 + k;
            t += (t >= 12);                 // skip center tap (i=2,j=2)
            const int i = t / 5;
            const int j = t - 5 * i;

            // HOT: fma screen (conservative; abs err <=7e-5 vs 1e-3 margin)
            float f0 = 0.f, f1 = 0.f, f2 = 0.f, f3 = 0.f;
#pragma unroll
            for (int q = 0; q < 8; ++q) {
                const uint2 p = smp[q][i][tx + j];
                const float t0 = cs[4 * q + 0] - lo_f(p.x);
                const float t1 = cs[4 * q + 1] - hi_f(p.x);
                const float t2 = cs[4 * q + 2] - lo_f(p.y);
                const float t3 = cs[4 * q + 3] - hi_f(p.y);
                f0 = fmaf(t0, t0, f0);
                f1 = fmaf(t1, t1, f1);
                f2 = fmaf(t2, t2, f2);
                f3 = fmaf(t3, t3, f3);
            }
            const float sq_fast = (f0 + f1) + (f2 + f3);

            if (sq_fast <= 18.001f) {
                // COLD (P~3e-5): exact numpy chain, verbatim R5 order
                const float rn = rd[i][tx + j];
                const float dd = fabsf(rc - rn);

                float r[8];
                {
#pragma clang fp contract(off)
#pragma unroll
                    for (int blk = 0; blk < 4; ++blk) {
                        const uint2 pe = smp[2 * blk][i][tx + j];
                        const uint2 po = smp[2 * blk + 1][i][tx + j];
                        float p;
                        p = cs[8 * blk + 0] - lo_f(pe.x); p = p * p; r[0] = blk ? r[0] + p : p;
                        p = cs[8 * blk + 1] - hi_f(pe.x); p = p * p; r[1] = blk ? r[1] + p : p;
                        p = cs[8 * blk + 2] - lo_f(pe.y); p = p * p; r[2] = blk ? r[2] + p : p;
                        p = cs[8 * blk + 3] - hi_f(pe.y); p = p * p; r[3] = blk ? r[3] + p : p;
                        p = cs[8 * blk + 4] - lo_f(po.x); p = p * p; r[4] = blk ? r[4] + p : p;
                        p = cs[8 * blk + 5] - hi_f(po.x); p = p * p; r[5] = blk ? r[5] + p : p;
                        p = cs[8 * blk + 6] - lo_f(po.y); p = p * p; r[6] = blk ? r[6] + p : p;
                        p = cs[8 * blk + 7] - hi_f(po.y); p = p * p; r[7] = blk ? r[7] + p : p;
                    }
                }
                const float sq = ((r[0] + r[1]) + (r[2] + r[3]))
                               + ((r[4] + r[5]) + (r[6] + r[7]));

                const float sd  = sqrtf(sq);
                const float ddc = fmaxf(dd, 1e-8f);
                const float sdc = fmaxf(sd, 1e-8f);

                if (ddc > 1e-8f && sdc > 1e-8f) {
                    const float s2 = sdc * sdc;
                    if (s2 <= 18.0f) {                  // else l_sem == 0 exactly
                        const float ls = (float)expm1(-(double)s2) + 1.0f;
                        const float ad = -(ddc / 10.0f);
                        const float ld = (float)expm1((double)ad) + 1.0f;
                        acc += 2.0 * (double)(ld * ls); // cnt == 2
                    }
                }
            }
        }
    }

    // block reduce (double) + ONE plain store per block
#pragma unroll
    for (int off = 32; off > 0; off >>= 1)
        acc += __shfl_down(acc, off);
    if ((tid & 63) == 0) wsum[tid >> 6] = acc;
    __syncthreads();
    if (tid == 0)
        partials[l] = wsum[0] + wsum[1] + wsum[2] + wsum[3];
}

__global__ __launch_bounds__(256) void dgp_fin(
    const double* __restrict__ partials, float* __restrict__ out)
{
    const int tid = threadIdx.x;
    double acc = 0.0;
    for (int k = tid; k < NBLK; k += 256)
        acc += partials[k];
#pragma unroll
    for (int off = 32; off > 0; off >>= 1)
        acc += __shfl_down(acc, off);
    __shared__ double ws[4];
    if ((tid & 63) == 0) ws[tid >> 6] = acc;
    __syncthreads();
    if (tid == 0)
        out[0] = (float)((ws[0] + ws[1] + ws[2] + ws[3]) / 3534400.0);
}

extern "C" void kernel_launch(void* const* d_in, const int* in_sizes, int n_in,
                              void* d_out, int out_size, void* d_ws, size_t ws_size,
                              hipStream_t stream)
{
    const float* S = (const float*)d_in[0];
    const float* D = (const float*)d_in[1];
    if (n_in >= 2 && in_sizes[0] < in_sizes[1]) {
        S = (const float*)d_in[1];
        D = (const float*)d_in[0];
    }
    double* partials = (double*)d_ws;   // 1128 * 8 B, every slot written

    dgp_tiled<<<NBLK, 256, 0, stream>>>(S, D, partials);
    dgp_fin<<<1, 256, 0, stream>>>(partials, (float*)d_out);
}

// Round 13
// 73.460 us; speedup vs baseline: 1.0083x; 1.0083x over previous
//
#include <hip/hip_runtime.h>
#include <math.h>

// DGP loss — ROUND 13: TH=2 (two output rows per block).
// R12 post-mortem: 2x occupancy from bf16-packed LDS was NEUTRAL -> kernel is
// NOT wave-starved; remaining cost is staging volume/latency (each output row
// re-stages 5 halo rows; y-neighbors share 4). TH=2 cuts staged rows per
// output row 5 -> 3 (-40% global fetch ~49->29 MB, -40% LDS writes); blocks
// halve to 564 (568 padded for the exact x8 XCD swizzle); packed LDS tile
// grows to 26 KB -> still 5 blocks/CU capacity.
// Keeps (all validated): XCD-contiguous y-runs (R11 -2.8us), max-MLP staging
// (R9 -8us), bf16-packed LDS (R12, lossless), plain per-block partials + fin
// kernel (R10: single-address atomics serialize), fma screen + cold exact
// numpy chain. Numerics locked: bit-exact R5-R12 (absmax 0.0).

#define HP    188
#define IMW   192
#define NCH   32
#define TW    64
#define HWC   68            // 64 + 4 halo cols
#define NR2   6             // 2 output rows + 4 halo rows
#define NYT   94            // y-tiles (188/2)
#define PLANE (IMW * IMW)
#define NWRK  (3 * NYT * 2) // 564 working blocks
#define NBLK  568           // padded to 71*8 for the XCD swizzle
#define NSLOT (8 * NR2 * HWC) // 3264 quad-slots (4 channels each)
#define SPT   13              // ceil(3264/256)

__device__ __forceinline__ unsigned bf16_bits(float f) {
    unsigned u = __float_as_uint(f);
    return (u + 0x7fffu + ((u >> 16) & 1u)) >> 16;   // RNE to bf16, bits
}
__device__ __forceinline__ float bf16_rne(float f) {
    unsigned u = __float_as_uint(f);
    u += 0x7fffu + ((u >> 16) & 1u);
    u &= 0xffff0000u;
    return __uint_as_float(u);
}
__device__ __forceinline__ float lo_f(unsigned p) { return __uint_as_float(p << 16); }
__device__ __forceinline__ float hi_f(unsigned p) { return __uint_as_float(p & 0xffff0000u); }

__global__ __launch_bounds__(256) void dgp_tiled(
    const float* __restrict__ S,   // [2,32,192,192] bf16-grid values in f32
    const float* __restrict__ D,   // [2,1,192,192]
    double* __restrict__ partials) // [NBLK] plain stores (every slot written)
{
    __shared__ __align__(8) uint2 smp[8][NR2][HWC];  // 26112 B packed bf16 x4
    __shared__ float  rd[NR2][HWC];                  // 1632 B
    __shared__ double wsum[4];

    const int tid = threadIdx.x;
    const int tx  = tid & 63;
    const int tg  = tid >> 6;

    // ---- XCD-aware tile decode: XCD (l&7) owns a contiguous y-tile run ----
    const int l   = blockIdx.x;          // 0..567
    const int xcd = l & 7;
    const int g   = xcd * 71 + (l >> 3); // contiguous per XCD
    if (g >= NWRK) {                     // padded block: publish 0, exit
        if (tid == 0) partials[l] = 0.0;
        return;
    }
    const int c   = g / NYT;             // column 0..5 = (b, xtile)
    const int oy0 = (g - c * NYT) * 2;   // first output row (0..186)
    const int b   = c / 3;
    const int ox0 = (c - 3 * b) * TW;

    // ---------- phase 1: issue ALL staging loads (max MLP) ----------
    float dv[2];
#pragma unroll
    for (int s = 0; s < 2; ++s) {
        const int t = tid + 256 * s;
        float d = 1.0f;
        if (t < NR2 * HWC) {
            const int i   = t / HWC;
            const int col = t - i * HWC;
            const int gc  = ox0 + col;
            if (gc < IMW) d = D[(b * IMW + (oy0 + i)) * IMW + gc];
        }
        dv[s] = d;
    }
    float4 sv[SPT];
#pragma unroll
    for (int s = 0; s < SPT; ++s) {
        const int t = tid + 256 * s;
        float4 v = make_float4(0.f, 0.f, 0.f, 0.f);
        if (t < NSLOT) {
            const int q   = t / (NR2 * HWC);
            const int rem = t - q * (NR2 * HWC);
            const int i   = rem / HWC;
            const int col = rem - i * HWC;
            const int gc  = ox0 + col;
            if (gc < IMW) {
                const int base = ((b * NCH + 4 * q) * IMW + (oy0 + i)) * IMW + gc;
                v.x = S[base];
                v.y = S[base + PLANE];
                v.z = S[base + 2 * PLANE];
                v.w = S[base + 3 * PLANE];
            }
        }
        sv[s] = v;
    }

    // ---------- phase 2: rne + pack + LDS write ----------
#pragma unroll
    for (int s = 0; s < 2; ++s) {
        const int t = tid + 256 * s;
        if (t < NR2 * HWC) {
            const int i   = t / HWC;
            const int col = t - i * HWC;
            rd[i][col] = 1.0f / (bf16_rne(dv[s]) + 1e-6f);
        }
    }
#pragma unroll
    for (int s = 0; s < SPT; ++s) {
        const int t = tid + 256 * s;
        if (t < NSLOT) {
            const int q   = t / (NR2 * HWC);
            const int rem = t - q * (NR2 * HWC);
            const int i   = rem / HWC;
            const int col = rem - i * HWC;
            const float4 v = sv[s];
            uint2 pk;
            pk.x = bf16_bits(v.x) | (__float_as_uint(bf16_rne(v.y)) & 0xffff0000u);
            pk.y = bf16_bits(v.z) | (__float_as_uint(bf16_rne(v.w)) & 0xffff0000u);
            smp[q][i][col] = pk;
        }
    }
    __syncthreads();

    // ---------- compute: 64 x-positions x 4 tap-groups x 2 output rows ----
    double acc = 0.0;
    const int ox = ox0 + tx;
    if (ox < HP) {
#pragma unroll
        for (int py = 0; py < 2; ++py) {
            float cs[NCH];
#pragma unroll
            for (int q = 0; q < 8; ++q) {
                const uint2 p = smp[q][py + 2][tx + 2];
                cs[4 * q + 0] = lo_f(p.x);
                cs[4 * q + 1] = hi_f(p.x);
                cs[4 * q + 2] = lo_f(p.y);
                cs[4 * q + 3] = hi_f(p.y);
            }
            const float rc = rd[py + 2][tx + 2];

            for (int k = 0; k < 6; ++k) {
                int t = tg * 6 + k;
                t += (t >= 12);                 // skip center tap (2,2)
                const int i = py + t / 5;
                const int j = t - 5 * (t / 5);

                // HOT: fma screen (conservative; err <=7e-5 vs 1e-3 margin)
                float f0 = 0.f, f1 = 0.f, f2 = 0.f, f3 = 0.f;
#pragma unroll
                for (int q = 0; q < 8; ++q) {
                    const uint2 p = smp[q][i][tx + j];
                    const float t0 = cs[4 * q + 0] - lo_f(p.x);
                    const float t1 = cs[4 * q + 1] - hi_f(p.x);
                    const float t2 = cs[4 * q + 2] - lo_f(p.y);
                    const float t3 = cs[4 * q + 3] - hi_f(p.y);
                    f0 = fmaf(t0, t0, f0);
                    f1 = fmaf(t1, t1, f1);
                    f2 = fmaf(t2, t2, f2);
                    f3 = fmaf(t3, t3, f3);
                }
                const float sq_fast = (f0 + f1) + (f2 + f3);

                if (sq_fast <= 18.001f) {
                    // COLD (P~3e-5): exact numpy chain, verbatim R5 order
                    const float rn = rd[i][tx + j];
                    const float dd = fabsf(rc - rn);

                    float r[8];
                    {
#pragma clang fp contract(off)
#pragma unroll
                        for (int blk = 0; blk < 4; ++blk) {
                            const uint2 pe = smp[2 * blk][i][tx + j];
                            const uint2 po = smp[2 * blk + 1][i][tx + j];
                            float p;
                            p = cs[8 * blk + 0] - lo_f(pe.x); p = p * p; r[0] = blk ? r[0] + p : p;
                            p = cs[8 * blk + 1] - hi_f(pe.x); p = p * p; r[1] = blk ? r[1] + p : p;
                            p = cs[8 * blk + 2] - lo_f(pe.y); p = p * p; r[2] = blk ? r[2] + p : p;
                            p = cs[8 * blk + 3] - hi_f(pe.y); p = p * p; r[3] = blk ? r[3] + p : p;
                            p = cs[8 * blk + 4] - lo_f(po.x); p = p * p; r[4] = blk ? r[4] + p : p;
                            p = cs[8 * blk + 5] - hi_f(po.x); p = p * p; r[5] = blk ? r[5] + p : p;
                            p = cs[8 * blk + 6] - lo_f(po.y); p = p * p; r[6] = blk ? r[6] + p : p;
                            p = cs[8 * blk + 7] - hi_f(po.y); p = p * p; r[7] = blk ? r[7] + p : p;
                        }
                    }
                    const float sq = ((r[0] + r[1]) + (r[2] + r[3]))
                                   + ((r[4] + r[5]) + (r[6] + r[7]));

                    const float sd  = sqrtf(sq);
                    const float ddc = fmaxf(dd, 1e-8f);
                    const float sdc = fmaxf(sd, 1e-8f);

                    if (ddc > 1e-8f && sdc > 1e-8f) {
                        const float s2 = sdc * sdc;
                        if (s2 <= 18.0f) {              // else l_sem == 0 exactly
                            const float ls = (float)expm1(-(double)s2) + 1.0f;
                            const float ad = -(ddc / 10.0f);
                            const float ld = (float)expm1((double)ad) + 1.0f;
                            acc += 2.0 * (double)(ld * ls); // cnt == 2
                        }
                    }
                }
            }
        }
    }

    // block reduce (double) + ONE plain store per block
#pragma unroll
    for (int off = 32; off > 0; off >>= 1)
        acc += __shfl_down(acc, off);
    if ((tid & 63) == 0) wsum[tid >> 6] = acc;
    __syncthreads();
    if (tid == 0)
        partials[l] = wsum[0] + wsum[1] + wsum[2] + wsum[3];
}

__global__ __launch_bounds__(256) void dgp_fin(
    const double* __restrict__ partials, float* __restrict__ out)
{
    const int tid = threadIdx.x;
    double acc = 0.0;
    for (int k = tid; k < NBLK; k += 256)
        acc += partials[k];
#pragma unroll
    for (int off = 32; off > 0; off >>= 1)
        acc += __shfl_down(acc, off);
    __shared__ double ws[4];
    if ((tid & 63) == 0) ws[tid >> 6] = acc;
    __syncthreads();
    if (tid == 0)
        out[0] = (float)((ws[0] + ws[1] + ws[2] + ws[3]) / 3534400.0);
}

extern "C" void kernel_launch(void* const* d_in, const int* in_sizes, int n_in,
                              void* d_out, int out_size, void* d_ws, size_t ws_size,
                              hipStream_t stream)
{
    const float* S = (const float*)d_in[0];
    const float* D = (const float*)d_in[1];
    if (n_in >= 2 && in_sizes[0] < in_sizes[1]) {
        S = (const float*)d_in[1];
        D = (const float*)d_in[0];
    }
    double* partials = (double*)d_ws;   // NBLK * 8 B, every slot written

    dgp_tiled<<<NBLK, 256, 0, stream>>>(S, D, partials);
    dgp_fin<<<1, 256, 0, stream>>>(partials, (float*)d_out);
}

// Round 14
// 71.540 us; speedup vs baseline: 1.0353x; 1.0268x over previous
//
#include <hip/hip_runtime.h>
#include <math.h>

// DGP loss — ROUND 14: symmetric-pair halving of the tap loop.
// f(c,t) is symmetric in the (center,tap) PIXEL pair (sd, dd symmetric;
// cnt==2 for every pixel since rd>0 always — locked since R5). Enumerate only
// the 12 positive-half offsets (ti>2 or ti==2&&tj>2):
//   w1 = 4 if mirror host t1 is interior (both coords in [2,189]), else 2;
//   plus a SINGLE extra term f(c, t2=c-δ) weight 2 when t2 is non-interior
//   (its would-be host doesn't exist) — only image-edge lanes/rows.
// x2/x4 exact in double; each fp32 term uses the verbatim locked chain ->
// bit-exact. Halves hot screens/thread 12 -> 6, LDS reads ~45%.
// Keeps: XCD-contiguous y-runs (R11), max-MLP staging (R9), bf16-packed LDS
// (R12), TH=2 (R13), plain partials + fin kernel (R10 lesson), fma screen +
// cold exact numpy chain. Numerics locked: absmax 0.0 R5-R13.

#define HP    188
#define IMW   192
#define NCH   32
#define TW    64
#define HWC   68            // 64 + 4 halo cols
#define NR2   6             // 2 output rows + 4 halo rows
#define NYT   94            // y-tiles (188/2)
#define PLANE (IMW * IMW)
#define NWRK  (3 * NYT * 2) // 564 working blocks
#define NBLK  568           // padded to 71*8 for the XCD swizzle
#define NSLOT (8 * NR2 * HWC) // 3264 quad-slots
#define SPT   13              // ceil(3264/256)

__device__ __forceinline__ unsigned bf16_bits(float f) {
    unsigned u = __float_as_uint(f);
    return (u + 0x7fffu + ((u >> 16) & 1u)) >> 16;
}
__device__ __forceinline__ float bf16_rne(float f) {
    unsigned u = __float_as_uint(f);
    u += 0x7fffu + ((u >> 16) & 1u);
    u &= 0xffff0000u;
    return __uint_as_float(u);
}
__device__ __forceinline__ float lo_f(unsigned p) { return __uint_as_float(p << 16); }
__device__ __forceinline__ float hi_f(unsigned p) { return __uint_as_float(p & 0xffff0000u); }

// 12 positive-half taps (ti,tj) in window coords, center = (2,2)
__constant__ int HTI[12] = {2,2,3,3,3,3,3,4,4,4,4,4};
__constant__ int HTJ[12] = {3,4,0,1,2,3,4,0,1,2,3,4};

__global__ __launch_bounds__(256) void dgp_tiled(
    const float* __restrict__ S,   // [2,32,192,192] bf16-grid values in f32
    const float* __restrict__ D,   // [2,1,192,192]
    double* __restrict__ partials) // [NBLK] plain stores (every slot written)
{
    __shared__ __align__(8) uint2 smp[8][NR2][HWC];  // 26112 B packed bf16 x4
    __shared__ float  rd[NR2][HWC];
    __shared__ double wsum[4];

    const int tid = threadIdx.x;
    const int tx  = tid & 63;
    const int tg  = tid >> 6;

    // ---- XCD-aware tile decode ----
    const int l   = blockIdx.x;          // 0..567
    const int xcd = l & 7;
    const int g   = xcd * 71 + (l >> 3);
    if (g >= NWRK) {
        if (tid == 0) partials[l] = 0.0;
        return;
    }
    const int c   = g / NYT;
    const int oy0 = (g - c * NYT) * 2;
    const int b   = c / 3;
    const int ox0 = (c - 3 * b) * TW;

    // ---------- phase 1: issue ALL staging loads (max MLP) ----------
    float dv[2];
#pragma unroll
    for (int s = 0; s < 2; ++s) {
        const int t = tid + 256 * s;
        float d = 1.0f;
        if (t < NR2 * HWC) {
            const int i   = t / HWC;
            const int col = t - i * HWC;
            const int gc  = ox0 + col;
            if (gc < IMW) d = D[(b * IMW + (oy0 + i)) * IMW + gc];
        }
        dv[s] = d;
    }
    float4 sv[SPT];
#pragma unroll
    for (int s = 0; s < SPT; ++s) {
        const int t = tid + 256 * s;
        float4 v = make_float4(0.f, 0.f, 0.f, 0.f);
        if (t < NSLOT) {
            const int q   = t / (NR2 * HWC);
            const int rem = t - q * (NR2 * HWC);
            const int i   = rem / HWC;
            const int col = rem - i * HWC;
            const int gc  = ox0 + col;
            if (gc < IMW) {
                const int base = ((b * NCH + 4 * q) * IMW + (oy0 + i)) * IMW + gc;
                v.x = S[base];
                v.y = S[base + PLANE];
                v.z = S[base + 2 * PLANE];
                v.w = S[base + 3 * PLANE];
            }
        }
        sv[s] = v;
    }

    // ---------- phase 2: rne + pack + LDS write ----------
#pragma unroll
    for (int s = 0; s < 2; ++s) {
        const int t = tid + 256 * s;
        if (t < NR2 * HWC) {
            const int i   = t / HWC;
            const int col = t - i * HWC;
            rd[i][col] = 1.0f / (bf16_rne(dv[s]) + 1e-6f);
        }
    }
#pragma unroll
    for (int s = 0; s < SPT; ++s) {
        const int t = tid + 256 * s;
        if (t < NSLOT) {
            const int q   = t / (NR2 * HWC);
            const int rem = t - q * (NR2 * HWC);
            const int i   = rem / HWC;
            const int col = rem - i * HWC;
            const float4 v = sv[s];
            uint2 pk;
            pk.x = bf16_bits(v.x) | (__float_as_uint(bf16_rne(v.y)) & 0xffff0000u);
            pk.y = bf16_bits(v.z) | (__float_as_uint(bf16_rne(v.w)) & 0xffff0000u);
            smp[q][i][col] = pk;
        }
    }
    __syncthreads();

    // ---------- compute ----------
    double acc = 0.0;
    const int ox = ox0 + tx;
    if (ox < HP) {
#pragma unroll
        for (int py = 0; py < 2; ++py) {
            float cs[NCH];
#pragma unroll
            for (int q = 0; q < 8; ++q) {
                const uint2 p = smp[q][py + 2][tx + 2];
                cs[4 * q + 0] = lo_f(p.x);
                cs[4 * q + 1] = hi_f(p.x);
                cs[4 * q + 2] = lo_f(p.y);
                cs[4 * q + 3] = hi_f(p.y);
            }
            const float rc = rd[py + 2][tx + 2];

            // one tap evaluation: LDS row i, col jc, weight w (2 or 4)
            auto eval_tap = [&](int i, int jc, float w) {
                // HOT: fma screen (conservative; err <=7e-5 vs 1e-3 margin)
                float f0 = 0.f, f1 = 0.f, f2 = 0.f, f3 = 0.f;
#pragma unroll
                for (int q = 0; q < 8; ++q) {
                    const uint2 p = smp[q][i][jc];
                    const float t0 = cs[4 * q + 0] - lo_f(p.x);
                    const float t1 = cs[4 * q + 1] - hi_f(p.x);
                    const float t2 = cs[4 * q + 2] - lo_f(p.y);
                    const float t3 = cs[4 * q + 3] - hi_f(p.y);
                    f0 = fmaf(t0, t0, f0);
                    f1 = fmaf(t1, t1, f1);
                    f2 = fmaf(t2, t2, f2);
                    f3 = fmaf(t3, t3, f3);
                }
                const float sq_fast = (f0 + f1) + (f2 + f3);

                if (sq_fast <= 18.001f) {
                    // COLD (P~3e-5): exact numpy chain, verbatim R5 order
                    const float rn = rd[i][jc];
                    const float dd = fabsf(rc - rn);
                    float r[8];
                    {
#pragma clang fp contract(off)
#pragma unroll
                        for (int blk = 0; blk < 4; ++blk) {
                            const uint2 pe = smp[2 * blk][i][jc];
                            const uint2 po = smp[2 * blk + 1][i][jc];
                            float p;
                            p = cs[8 * blk + 0] - lo_f(pe.x); p = p * p; r[0] = blk ? r[0] + p : p;
                            p = cs[8 * blk + 1] - hi_f(pe.x); p = p * p; r[1] = blk ? r[1] + p : p;
                            p = cs[8 * blk + 2] - lo_f(pe.y); p = p * p; r[2] = blk ? r[2] + p : p;
                            p = cs[8 * blk + 3] - hi_f(pe.y); p = p * p; r[3] = blk ? r[3] + p : p;
                            p = cs[8 * blk + 4] - lo_f(po.x); p = p * p; r[4] = blk ? r[4] + p : p;
                            p = cs[8 * blk + 5] - hi_f(po.x); p = p * p; r[5] = blk ? r[5] + p : p;
                            p = cs[8 * blk + 6] - lo_f(po.y); p = p * p; r[6] = blk ? r[6] + p : p;
                            p = cs[8 * blk + 7] - hi_f(po.y); p = p * p; r[7] = blk ? r[7] + p : p;
                        }
                    }
                    const float sq = ((r[0] + r[1]) + (r[2] + r[3]))
                                   + ((r[4] + r[5]) + (r[6] + r[7]));
                    const float sd  = sqrtf(sq);
                    const float ddc = fmaxf(dd, 1e-8f);
                    const float sdc = fmaxf(sd, 1e-8f);
                    if (ddc > 1e-8f && sdc > 1e-8f) {
                        const float s2 = sdc * sdc;
                        if (s2 <= 18.0f) {              // else l_sem == 0 exactly
                            const float ls = (float)expm1(-(double)s2) + 1.0f;
                            const float ad = -(ddc / 10.0f);
                            const float ld = (float)expm1((double)ad) + 1.0f;
                            acc += (double)w * (double)(ld * ls);
                        }
                    }
                }
            };

#pragma unroll
            for (int m = 0; m < 3; ++m) {
                const int t  = tg * 3 + m;      // 12 half-taps over 4 groups
                const int ti = HTI[t];
                const int tj = HTJ[t];

                // t1 = c + delta: LDS (py+ti, tx+tj); pixel (oy0+py+ti, ox0+tx+tj)
                const int i1    = py + ti;
                const int j1    = tx + tj;
                const int t1row = oy0 + i1;
                const int t1col = ox0 + j1;
                const float w1  = (t1row <= 189 && t1col >= 2 && t1col <= 189)
                                ? 4.0f : 2.0f;   // mirror host interior -> pair
                eval_tap(i1, j1, w1);

                // t2 = c - delta: single extra ONLY if its host is non-interior
                const int i2    = py + 4 - ti;
                const int j2    = tx + 4 - tj;
                const int t2row = oy0 + i2;
                const int t2col = ox0 + j2;
                if (t2row < 2 || t2col < 2 || t2col > 189)
                    eval_tap(i2, j2, 2.0f);
            }
        }
    }

    // block reduce (double) + ONE plain store per block
#pragma unroll
    for (int off = 32; off > 0; off >>= 1)
        acc += __shfl_down(acc, off);
    if ((tid & 63) == 0) wsum[tid >> 6] = acc;
    __syncthreads();
    if (tid == 0)
        partials[l] = wsum[0] + wsum[1] + wsum[2] + wsum[3];
}

__global__ __launch_bounds__(256) void dgp_fin(
    const double* __restrict__ partials, float* __restrict__ out)
{
    const int tid = threadIdx.x;
    double acc = 0.0;
    for (int k = tid; k < NBLK; k += 256)
        acc += partials[k];
#pragma unroll
    for (int off = 32; off > 0; off >>= 1)
        acc += __shfl_down(acc, off);
    __shared__ double ws[4];
    if ((tid & 63) == 0) ws[tid >> 6] = acc;
    __syncthreads();
    if (tid == 0)
        out[0] = (float)((ws[0] + ws[1] + ws[2] + ws[3]) / 3534400.0);
}

extern "C" void kernel_launch(void* const* d_in, const int* in_sizes, int n_in,
                              void* d_out, int out_size, void* d_ws, size_t ws_size,
                              hipStream_t stream)
{
    const float* S = (const float*)d_in[0];
    const float* D = (const float*)d_in[1];
    if (n_in >= 2 && in_sizes[0] < in_sizes[1]) {
        S = (const float*)d_in[1];
        D = (const float*)d_in[0];
    }
    double* partials = (double*)d_ws;   // NBLK * 8 B, every slot written

    dgp_tiled<<<NBLK, 256, 0, stream>>>(S, D, partials);
    dgp_fin<<<1, 256, 0, stream>>>(partials, (float*)d_out);
}